// Round 6
// baseline (613.478 us; speedup 1.0000x reference)
//
#include <hip/hip_runtime.h>
#include <hip/hip_bf16.h>

// GraphSAGE 2-layer, N=100000, E=1.6M, D=128. f32 I/O, bf16 MFMA compute.
//
// R14: R13 post-mortem: whole-CSR mega-kernel collapsed to 1.5 blocks/CU ->
// latency-bound streaming/scan phases (251us, VALUBusy 1.6%). Grid-barrier
// fusion is only safe for latency-TOLERANT phases (deep batched gathers).
// Also learned: gemms cost ~45-55us each (R13 arithmetic), copy/latency
// bound (64KB B-copy per block, 2 blocks/CU), not traffic-bound.
// R14: (a) CSR build back to R12 separate dispatches, minus bucket_scan
// (partition/csrbuild redo a cheap 512-wide bucketCnt scan in LDS);
// (b) per layer, ONE kernel: {B->LDS; grid-stride agg (R8 16-deep inner
// loop, 512 blocks x 4 waves); ONE grid barrier; grid-stride gemm tiles}.
// Agg phase at 8 waves/CU still saturates the measured ~2.4 req/cy/XCD L2
// request cap (32 lines in flight per wave). Kills 2 gemm dispatches, their
// B-copies ride before the agg phase. 9 -> 6 dispatches.
//
// Pipeline: bucket_count -> blk_scan (zeroes bar) -> partition+wprep ->
//   csrbuild+cvt -> fused1 (agg|bar|gemm, relu->h1b) -> fused2 -> d_out.
//   Fallback layout B (small ws): f32 gathers, separate gemm, h1 in d_out.

typedef __attribute__((ext_vector_type(8))) short short8;
typedef __attribute__((ext_vector_type(4))) float float4_;

#define NBMAX 512  // max buckets (256 nodes each) -> N <= 131072

__device__ __forceinline__ unsigned short f2bf(float f) {
    unsigned int u = __float_as_uint(f);
    unsigned int r = (u + 0x7FFFu + ((u >> 16) & 1u)) >> 16;
    return (unsigned short)r;
}

// Software grid barrier: monotonic counter (bar zeroed by blk_scan each
// launch). Device-scope atomics + threadfence cross XCDs.
__device__ __forceinline__ void gbar(int* bar, int id, int G) {
    __syncthreads();
    if (threadIdx.x == 0) {
        __threadfence();
        atomicAdd(&bar[id], 1);
        while (atomicAdd(&bar[id], 0) < G) __builtin_amdgcn_s_sleep(16);
        __threadfence();
    }
    __syncthreads();
}

// ---------------- phase 1a: per-block bucket histogram ---------------------
__global__ __launch_bounds__(256) void bucket_count(const int* __restrict__ dst, int E, int NB,
                                                    int* __restrict__ hist) {
    __shared__ int h[NBMAX];
    int tid = threadIdx.x;
    for (int b = tid; b < NB; b += 256) h[b] = 0;
    __syncthreads();
    int base = blockIdx.x * 4096;
    for (int i = 0; i < 16; i++) {
        int e = base + i * 256 + tid;
        if (e < E) atomicAdd(&h[dst[e] >> 8], 1);
    }
    __syncthreads();
    int* out = hist + (size_t)blockIdx.x * NB;
    for (int b = tid; b < NB; b += 256) out[b] = h[b];
}

// ---------------- phase 1b: cross-block scan per bucket --------------------
// Block b scans hist[0..nblk)[b] -> baseT[blk][b] (exclusive) + bucketCnt[b].
// Block 0 also zeroes the grid-barrier counters for the fused layers.
__global__ __launch_bounds__(256) void blk_scan(const int* __restrict__ hist, int nblk, int NB,
                                                int* __restrict__ baseT,
                                                int* __restrict__ bucketCnt,
                                                int* __restrict__ bar) {
    __shared__ int sd[256];
    __shared__ int carryS;
    int b = blockIdx.x, tid = threadIdx.x;
    if (b == 0 && tid < 16) bar[tid] = 0;
    if (tid == 0) carryS = 0;
    __syncthreads();
    for (int c0 = 0; c0 < nblk; c0 += 256) {
        int i = c0 + tid;
        int v = (i < nblk) ? hist[(size_t)i * NB + b] : 0;
        sd[tid] = v;
        __syncthreads();
        for (int off = 1; off < 256; off <<= 1) {
            int x = sd[tid];
            int y = (tid >= off) ? sd[tid - off] : 0;
            __syncthreads();
            sd[tid] = x + y;
            __syncthreads();
        }
        int carry = carryS;
        if (i < nblk) baseT[(size_t)i * NB + b] = carry + sd[tid] - v;
        __syncthreads();
        if (tid == 255) carryS = carry + sd[255];
        __syncthreads();
    }
    if (tid == 0) bucketCnt[b] = carryS;
}

// In-block exclusive scan of bucketCnt[0..NB) -> bOffs (2 buckets/thread).
// Caller must __syncthreads-safe: uses sc[], writes bOffs[].
__device__ __forceinline__ void scan_buckets(const int* __restrict__ bucketCnt, int NB,
                                             int* bOffs, int* sc) {
    int tid = threadIdx.x;
    int b0 = 2 * tid, b1 = 2 * tid + 1;
    int c0 = (b0 < NB) ? bucketCnt[b0] : 0;
    int c1 = (b1 < NB) ? bucketCnt[b1] : 0;
    int ts = c0 + c1;
    sc[tid] = ts;
    __syncthreads();
    for (int off = 1; off < 256; off <<= 1) {
        int x = sc[tid];
        int y = (tid >= off) ? sc[tid - off] : 0;
        __syncthreads();
        sc[tid] = x + y;
        __syncthreads();
    }
    int excl = sc[tid] - ts;
    bOffs[b0] = excl;
    bOffs[b1] = excl + c0;
    __syncthreads();
}

// ---------------- phase 1c: partition edges + (tail blocks) weight prep ----
__global__ __launch_bounds__(256) void partition_wprep(
    const int* __restrict__ src, const int* __restrict__ dst, int E, int NB, int partBlocks,
    const int* __restrict__ bucketCnt, const int* __restrict__ baseT,
    unsigned int* __restrict__ bucketBuf,
    const float* __restrict__ Wn1, const float* __restrict__ Ws1,
    const float* __restrict__ bn1, const float* __restrict__ bs1,
    const float* __restrict__ Wn2, const float* __restrict__ Ws2,
    const float* __restrict__ bn2, const float* __restrict__ bs2,
    unsigned short* __restrict__ Bpre, float* __restrict__ biasPre) {
    int tid = threadIdx.x;
    if ((int)blockIdx.x >= partBlocks) {
        // ---- weight prep: f32 W -> bf16 pre-swizzled fragments ----
        int wb = blockIdx.x - partBlocks;  // [0,32)
        int l = wb >> 4;
        const float* Wn = l ? Wn2 : Wn1;
        const float* Ws = l ? Ws2 : Ws1;
        int fi = (wb & 15) * 256 + tid;
        int kt = fi >> 9;
        int nt = (fi >> 6) & 7;
        int lane = fi & 63;
        int o = nt * 16 + (lane & 15);
        int k = kt * 32 + (lane >> 4) * 8;
        const float* srcp = (k < 128) ? (Wn + o * 128 + k) : (Ws + o * 128 + (k - 128));
        short8 v;
#pragma unroll
        for (int j = 0; j < 8; j++) v[j] = (short)f2bf(srcp[j]);
        ((short8*)(Bpre + (size_t)l * 32768))[fi] = v;
        if ((wb & 15) == 0 && tid < 128) {
            const float* bn = l ? bn2 : bn1;
            const float* bs = l ? bs2 : bs1;
            biasPre[l * 128 + tid] = bn[tid] + bs[tid];
        }
        return;
    }
    __shared__ int cnt[NBMAX];
    __shared__ int bOffs[NBMAX];
    __shared__ int gb[NBMAX];
    __shared__ int sc[256];
    scan_buckets(bucketCnt, NB, bOffs, sc);
    for (int b = tid; b < NB; b += 256) {
        cnt[b] = 0;
        gb[b] = bOffs[b] + baseT[(size_t)blockIdx.x * NB + b];
    }
    __syncthreads();
    int eb = blockIdx.x * 4096;
    unsigned int pk[16];
    int bk[16], rk[16];
    for (int i = 0; i < 16; i++) {
        int e = eb + i * 256 + tid;
        if (e < E) {
            int d = dst[e];
            bk[i] = d >> 8;
            pk[i] = (unsigned)src[e] | ((unsigned)(d & 255) << 24);
            rk[i] = atomicAdd(&cnt[bk[i]], 1);
        } else {
            bk[i] = -1;
        }
    }
    __syncthreads();
    for (int i = 0; i < 16; i++)
        if (bk[i] >= 0) bucketBuf[gb[bk[i]] + rk[i]] = pk[i];
}

// ---------------- phase 2: per-bucket CSR build + (tail blocks) x->bf16 ----
__global__ __launch_bounds__(256) void csrbuild_cvt(
    const unsigned int* __restrict__ bucketBuf, const int* __restrict__ bucketCnt,
    int N, int NB, int* __restrict__ deg, int* __restrict__ offs, int* __restrict__ sortedSrc,
    const float* __restrict__ xin, unsigned int* __restrict__ xb, int n2) {
    int tid = threadIdx.x;
    if ((int)blockIdx.x >= NB) {
        // ---- cvt: f32 [N,128] -> packed bf16 u32 [N,64], 8 u32/thread ----
        int cb = blockIdx.x - NB;
        int base = cb * 2048 + tid;
        if (xb) {
#pragma unroll
            for (int i = 0; i < 8; i++) {
                int t = base + i * 256;
                if (t < n2) {
                    float2 v = ((const float2*)xin)[t];
                    xb[t] = (unsigned)f2bf(v.x) | ((unsigned)f2bf(v.y) << 16);
                }
            }
        }
        return;
    }
    __shared__ int bOffs[NBMAX];
    __shared__ int h[256];
    __shared__ int sc[256];
    __shared__ int cur[256];
    scan_buckets(bucketCnt, NB, bOffs, sc);
    int b = blockIdx.x;
    int n0 = b << 8;
    int bo = bOffs[b];
    int cnt = bucketCnt[b];
    h[tid] = 0;
    __syncthreads();
    for (int i = tid; i < cnt; i += 256) atomicAdd(&h[bucketBuf[bo + i] >> 24], 1);
    __syncthreads();
    int v = h[tid];
    sc[tid] = v;
    __syncthreads();
    for (int off = 1; off < 256; off <<= 1) {
        int x = sc[tid];
        int y = (tid >= off) ? sc[tid - off] : 0;
        __syncthreads();
        sc[tid] = x + y;
        __syncthreads();
    }
    int excl = sc[tid] - v;
    cur[tid] = bo + excl;
    int n = n0 + tid;
    if (n < N) {
        deg[n] = v;
        offs[n] = bo + excl;
    }
    __syncthreads();
    for (int i = tid; i < cnt; i += 256) {
        unsigned int pv = bucketBuf[bo + i];
        int pos = atomicAdd(&cur[pv >> 24], 1);
        sortedSrc[pos] = (int)(pv & 0xFFFFFFu);
    }
}

// ---------------- fused layer: {B->LDS; agg; grid-bar; gemm tiles} ---------
// table: node-major packed bf16 [N][64 u32] (gather + self source).
// Agg phase: grid-stride wave/node, R8 16-deep inner loop -> Aagg.
// Gemm phase: grid-stride 128-row tiles, MFMA vs resident 64KB B.
// G=512 blocks (2/CU via 64.5KB LDS) -> all co-resident for gbar.
__global__ __launch_bounds__(256) void fused_agg_gemm(
    const unsigned int* __restrict__ table,
    const int* __restrict__ deg, const int* __restrict__ offs,
    const int* __restrict__ sortedSrc, unsigned int* __restrict__ Aagg,
    const unsigned short* __restrict__ Bpre, const float* __restrict__ biasPre,
    void* Out, int relu, int outBf16, int Nn, int G, int* __restrict__ bar, int barId) {
    __shared__ unsigned short ldsB[32768];  // 64 KB
    __shared__ float biasS[128];
    int tid = threadIdx.x;

    // B copy first (coalesced; visibility ensured by gbar's syncthreads)
#pragma unroll
    for (int i = 0; i < 16; i++) {
        int fi = tid + 256 * i;
        ((short8*)ldsB)[fi] = ((const short8*)Bpre)[fi];
    }
    if (tid < 128) biasS[tid] = biasPre[tid];

    int wave = tid >> 6, lane = tid & 63;

    // ---- agg phase: grid-stride wave/node ----
    for (int n = blockIdx.x * 4 + wave; n < Nn; n += G * 4) {
        int d = deg[n], st = offs[n];
        float a0 = 0.f, a1 = 0.f;
        int j = 0;
        for (; j + 16 <= d; j += 16) {
            unsigned int uu[16];
#pragma unroll
            for (int u = 0; u < 16; u++) {
                int s = __builtin_amdgcn_readfirstlane(sortedSrc[st + j + u]);
                uu[u] = (table + (size_t)s * 64)[lane];
            }
#pragma unroll
            for (int u = 0; u < 16; u++) {
                a0 += __uint_as_float(uu[u] << 16);
                a1 += __uint_as_float(uu[u] & 0xFFFF0000u);
            }
        }
        for (; j + 8 <= d; j += 8) {
            unsigned int uu[8];
#pragma unroll
            for (int u = 0; u < 8; u++) {
                int s = __builtin_amdgcn_readfirstlane(sortedSrc[st + j + u]);
                uu[u] = (table + (size_t)s * 64)[lane];
            }
#pragma unroll
            for (int u = 0; u < 8; u++) {
                a0 += __uint_as_float(uu[u] << 16);
                a1 += __uint_as_float(uu[u] & 0xFFFF0000u);
            }
        }
        for (; j < d; j++) {
            int s = __builtin_amdgcn_readfirstlane(sortedSrc[st + j]);
            unsigned int u = (table + (size_t)s * 64)[lane];
            a0 += __uint_as_float(u << 16);
            a1 += __uint_as_float(u & 0xFFFF0000u);
        }
        float inv = 1.0f / (float)max(d, 1);
        Aagg[(size_t)n * 64 + lane] = (unsigned)f2bf(a0 * inv) | ((unsigned)f2bf(a1 * inv) << 16);
    }

    gbar(bar, barId, G);  // all Aagg rows visible to all blocks

    // ---- gemm phase: grid-stride 128-row tiles ----
    int quad = lane >> 4, mr = lane & 15;
    const unsigned short* Aa = (const unsigned short*)Aagg;
    const unsigned short* As = (const unsigned short*)table;
    int nTiles = (Nn + 127) >> 7;
    for (int t = blockIdx.x; t < nTiles; t += G) {
        int rowBase = t * 128 + wave * 32;
        float4_ acc[2][8];
        float4_ z = {0.f, 0.f, 0.f, 0.f};
        for (int mt = 0; mt < 2; mt++)
            for (int nt = 0; nt < 8; nt++) acc[mt][nt] = z;
        for (int kt = 0; kt < 8; kt++) {
            int kk = (kt & 3) * 32 + quad * 8;
            short8 a[2];
            for (int mt = 0; mt < 2; mt++) {
                int row = rowBase + mt * 16 + mr;
                if (row >= Nn) row = Nn - 1;  // in-bounds; result discarded
                const unsigned short* ap = (kt < 4) ? Aa : As;
                a[mt] = *(const short8*)(ap + (size_t)row * 128 + kk);
            }
            for (int nt = 0; nt < 8; nt++) {
                short8 b = *(const short8*)(ldsB + ((size_t)(kt * 8 + nt) * 64 + lane) * 8);
                acc[0][nt] = __builtin_amdgcn_mfma_f32_16x16x32_bf16(a[0], b, acc[0][nt], 0, 0, 0);
                acc[1][nt] = __builtin_amdgcn_mfma_f32_16x16x32_bf16(a[1], b, acc[1][nt], 0, 0, 0);
            }
        }
        // C/D layout: col = lane&15, row = (lane>>4)*4 + reg
        for (int mt = 0; mt < 2; mt++) {
            for (int nt = 0; nt < 8; nt++) {
                int col = nt * 16 + mr;
                float bv = biasS[col];
                for (int r = 0; r < 4; r++) {
                    int row = rowBase + mt * 16 + quad * 4 + r;
                    if (row < Nn) {
                        float v = acc[mt][nt][r] + bv;
                        if (relu) v = fmaxf(v, 0.f);
                        if (outBf16)
                            ((unsigned short*)Out)[(size_t)row * 128 + col] = f2bf(v);
                        else
                            ((float*)Out)[(size_t)row * 128 + col] = v;
                    }
                }
            }
        }
    }
}

// ---------------- mean agg, f32 source (fallback layout B) ------------------
__global__ __launch_bounds__(256) void agg_f32_kernel(
    const float* __restrict__ srcFeats,
    const int* __restrict__ deg, const int* __restrict__ offs,
    const int* __restrict__ sortedSrc,
    unsigned int* __restrict__ dst, int Nn) {
    int wave = threadIdx.x >> 6, lane = threadIdx.x & 63;
    int n = blockIdx.x * 4 + wave;
    if (n >= Nn) return;
    int d = deg[n], st = offs[n];
    float a0 = 0.f, a1 = 0.f;
    int j = 0;
    for (; j + 8 <= d; j += 8) {
        float2 v[8];
#pragma unroll
        for (int u = 0; u < 8; u++) {
            int s = __builtin_amdgcn_readfirstlane(sortedSrc[st + j + u]);
            v[u] = ((const float2*)(srcFeats + (size_t)s * 128))[lane];
        }
#pragma unroll
        for (int u = 0; u < 8; u++) {
            a0 += v[u].x;
            a1 += v[u].y;
        }
    }
    for (; j < d; j++) {
        int s = __builtin_amdgcn_readfirstlane(sortedSrc[st + j]);
        float2 v = ((const float2*)(srcFeats + (size_t)s * 128))[lane];
        a0 += v.x;
        a1 += v.y;
    }
    float inv = 1.0f / (float)max(d, 1);
    dst[(size_t)n * 64 + lane] = (unsigned)f2bf(a0 * inv) | ((unsigned)f2bf(a1 * inv) << 16);
}

// ---------------- fallback GEMM (layout B): node-major, f32 self -----------
// Out may alias Aself (layer 2): each wave reads only its own 32 rows before
// writing them -> safe. (No __restrict__ on Aself/Out.)
__global__ __launch_bounds__(256) void gemm_kernel(
    const unsigned short* __restrict__ Aagg, const void* Aself,
    const unsigned short* __restrict__ Bpre, const float* __restrict__ biasPre,
    void* Out, int relu, int selfF32, int outBf16, int Nrows) {
    __shared__ unsigned short ldsB[8 * 8 * 64 * 8];  // 64 KB
    __shared__ float biasS[128];
    int tid = threadIdx.x;
#pragma unroll
    for (int i = 0; i < 16; i++) {
        int fi = tid + 256 * i;
        ((short8*)ldsB)[fi] = ((const short8*)Bpre)[fi];
    }
    if (tid < 128) biasS[tid] = biasPre[tid];
    __syncthreads();

    int wave = tid >> 6, lane = tid & 63;
    int quad = lane >> 4, mr = lane & 15;
    int rowBase = blockIdx.x * 128 + wave * 32;

    float4_ acc[2][8];
    float4_ z = {0.f, 0.f, 0.f, 0.f};
    for (int mt = 0; mt < 2; mt++)
        for (int nt = 0; nt < 8; nt++) acc[mt][nt] = z;

    for (int kt = 0; kt < 8; kt++) {
        int kk = (kt & 3) * 32 + quad * 8;
        short8 a[2];
        for (int mt = 0; mt < 2; mt++) {
            int row = rowBase + mt * 16 + mr;
            if (row >= Nrows) row = Nrows - 1;
            if (kt < 4) {
                a[mt] = *(const short8*)(Aagg + (size_t)row * 128 + kk);
            } else if (selfF32) {
                const float* p = (const float*)Aself + (size_t)row * 128 + kk;
                float4_ f0 = *(const float4_*)p;
                float4_ f1 = *(const float4_*)(p + 4);
                short8 t;
#pragma unroll
                for (int j = 0; j < 4; j++) {
                    t[j] = (short)f2bf(f0[j]);
                    t[4 + j] = (short)f2bf(f1[j]);
                }
                a[mt] = t;
            } else {
                a[mt] = *(const short8*)((const unsigned short*)Aself + (size_t)row * 128 + kk);
            }
        }
        for (int nt = 0; nt < 8; nt++) {
            short8 b = *(const short8*)(ldsB + ((size_t)(kt * 8 + nt) * 64 + lane) * 8);
            acc[0][nt] = __builtin_amdgcn_mfma_f32_16x16x32_bf16(a[0], b, acc[0][nt], 0, 0, 0);
            acc[1][nt] = __builtin_amdgcn_mfma_f32_16x16x32_bf16(a[1], b, acc[1][nt], 0, 0, 0);
        }
    }
    for (int mt = 0; mt < 2; mt++) {
        for (int nt = 0; nt < 8; nt++) {
            int col = nt * 16 + mr;
            float bv = biasS[col];
            for (int r = 0; r < 4; r++) {
                int row = rowBase + mt * 16 + quad * 4 + r;
                if (row < Nrows) {
                    float v = acc[mt][nt][r] + bv;
                    if (relu) v = fmaxf(v, 0.f);
                    if (outBf16)
                        ((unsigned short*)Out)[(size_t)row * 128 + col] = f2bf(v);
                    else
                        ((float*)Out)[(size_t)row * 128 + col] = v;
                }
            }
        }
    }
}

extern "C" void kernel_launch(void* const* d_in, const int* in_sizes, int n_in,
                              void* d_out, int out_size, void* d_ws, size_t ws_size,
                              hipStream_t stream) {
    const float* x = (const float*)d_in[0];
    const int* ei = (const int*)d_in[1];
    const float* Wn1 = (const float*)d_in[2];
    const float* bn1 = (const float*)d_in[3];
    const float* Ws1 = (const float*)d_in[4];
    const float* bs1 = (const float*)d_in[5];
    const float* Wn2 = (const float*)d_in[6];
    const float* bn2 = (const float*)d_in[7];
    const float* Ws2 = (const float*)d_in[8];
    const float* bs2 = (const float*)d_in[9];

    const int N = in_sizes[0] / 128;
    const int E = in_sizes[1] / 2;
    const int* srcI = ei;
    const int* dstI = ei + E;
    const int NB = (N + 255) >> 8;      // <= NBMAX for N <= 131072
    const int ebBlocks = (E + 4095) / 4096;

    char* ws = (char*)d_ws;
    size_t off = 0;
    auto alloc = [&](size_t bytes) -> void* {
        void* p = ws + off;
        off += (bytes + 255) & ~(size_t)255;
        return p;
    };
    int* deg = (int*)alloc((size_t)N * 4);
    int* offs = (int*)alloc((size_t)N * 4);
    int* bucketCnt = (int*)alloc((NBMAX + 1) * 4);
    int* bar = (int*)alloc(16 * 4);
    int* hist = (int*)alloc((size_t)ebBlocks * NB * 4);
    int* baseT = (int*)alloc((size_t)ebBlocks * NB * 4);
    unsigned short* Bpre = (unsigned short*)alloc(2 * 32768 * 2);
    float* biasPre = (float*)alloc(2 * 128 * 4);
    int* sortedSrc = (int*)alloc((size_t)E * 4);
    unsigned short* Aagg = (unsigned short*)alloc((size_t)N * 128 * 2);
    size_t baseNeed = off;
    size_t bf16Buf = ((size_t)N * 128 * 2 + 255) & ~(size_t)255;
    bool bigWs = (ws_size >= baseNeed + 2 * bf16Buf);
    unsigned int* xb = nullptr;
    unsigned short* h1b = nullptr;
    if (bigWs) {
        xb = (unsigned int*)alloc((size_t)N * 128 * 2);
        h1b = (unsigned short*)alloc((size_t)N * 128 * 2);
    }
    // bucketBuf (E u32, 6.4 MB) aliases Aagg (dead until agg1)
    unsigned int* bucketBuf = (unsigned int*)Aagg;

    // ---- CSR build (atomic-free bucketing, self-scanned offsets) ----
    int n2 = N * 64;
    int cvtBlocks = bigWs ? (n2 + 2047) / 2048 : 0;
    bucket_count<<<ebBlocks, 256, 0, stream>>>(dstI, E, NB, hist);
    blk_scan<<<NB, 256, 0, stream>>>(hist, ebBlocks, NB, baseT, bucketCnt, bar);
    partition_wprep<<<ebBlocks + 32, 256, 0, stream>>>(
        srcI, dstI, E, NB, ebBlocks, bucketCnt, baseT, bucketBuf,
        Wn1, Ws1, bn1, bs1, Wn2, Ws2, bn2, bs2, Bpre, biasPre);
    csrbuild_cvt<<<NB + cvtBlocks, 256, 0, stream>>>(bucketBuf, bucketCnt, N, NB, deg, offs,
                                                     sortedSrc, x, xb, n2);

    if (bigWs) {
        // Fused agg+gemm per layer: 512 blocks (2/CU), one grid barrier.
        const int G = 512;
        fused_agg_gemm<<<G, 256, 0, stream>>>(xb, deg, offs, sortedSrc,
                                              (unsigned int*)Aagg, Bpre, biasPre,
                                              h1b, 1, 1, N, G, bar, 0);
        fused_agg_gemm<<<G, 256, 0, stream>>>((const unsigned int*)h1b, deg, offs, sortedSrc,
                                              (unsigned int*)Aagg, Bpre + 32768, biasPre + 128,
                                              d_out, 0, 0, N, G, bar, 1);
    } else {
        // Layout B: f32 gathers, h1 f32 staged in d_out
        int aggBlocks = (N + 3) / 4;
        int gemmBlocks = (N + 127) / 128;
        float* h1 = (float*)d_out;
        agg_f32_kernel<<<aggBlocks, 256, 0, stream>>>(x, deg, offs, sortedSrc,
                                                      (unsigned int*)Aagg, N);
        gemm_kernel<<<gemmBlocks, 256, 0, stream>>>(Aagg, x, Bpre, biasPre, h1, 1, 1, 0, N);
        agg_f32_kernel<<<aggBlocks, 256, 0, stream>>>(h1, deg, offs, sortedSrc,
                                                      (unsigned int*)Aagg, N);
        gemm_kernel<<<gemmBlocks, 256, 0, stream>>>(Aagg, h1, Bpre + 32768, biasPre + 128,
                                                    d_out, 0, 1, 0, N);
    }
}

// Round 7
// 348.193 us; speedup vs baseline: 1.7619x; 1.7619x over previous
//
#include <hip/hip_runtime.h>
#include <hip/hip_bf16.h>

// GraphSAGE 2-layer, N=100000, E=1.6M, D=128. f32 I/O, bf16 MFMA compute.
//
// R15: R14 post-mortem: fused agg+gemm ran at 8 waves/CU -> gather fill
// rate 3.6x below cap. LAW (confirmed R10+R14): the gather needs ~16-21
// free-running waves/CU; never fuse it under a big-LDS/barrier structure.
// Accounting (R12/R14): aggs 139us (floor), CSR chain ~112us, gemms ~95us
// (~47 each, 3x above their ~15us traffic+MFMA roofline -> A-load latency
// serialized per kt iteration at 8 waves/CU, VGPR=88 shows no hoisting).
// R15 = R12 structure + (a) 4-dispatch CSR (scan_buckets in LDS instead of
// bucket_scan dispatch), (b) gemm prefetches ALL 16 A fragments (static
// unroll, +64 VGPR) before the MFMA loop -> one load-wait instead of 8.
//
// Pipeline (8 dispatches): bucket_count -> blk_scan -> partition+wprep ->
//   csrbuild+cvt -> agg1 -> gemm1(relu->h1b) -> agg2 -> gemm2 -> d_out.
//   Fallback layout B (small ws): f32 gathers, h1 f32 staged in d_out.

typedef __attribute__((ext_vector_type(8))) short short8;
typedef __attribute__((ext_vector_type(4))) float float4_;

#define NBMAX 512  // max buckets (256 nodes each) -> N <= 131072

__device__ __forceinline__ unsigned short f2bf(float f) {
    unsigned int u = __float_as_uint(f);
    unsigned int r = (u + 0x7FFFu + ((u >> 16) & 1u)) >> 16;
    return (unsigned short)r;
}

// ---------------- phase 1a: per-block bucket histogram ---------------------
__global__ __launch_bounds__(256) void bucket_count(const int* __restrict__ dst, int E, int NB,
                                                    int* __restrict__ hist) {
    __shared__ int h[NBMAX];
    int tid = threadIdx.x;
    for (int b = tid; b < NB; b += 256) h[b] = 0;
    __syncthreads();
    int base = blockIdx.x * 4096;
    for (int i = 0; i < 16; i++) {
        int e = base + i * 256 + tid;
        if (e < E) atomicAdd(&h[dst[e] >> 8], 1);
    }
    __syncthreads();
    int* out = hist + (size_t)blockIdx.x * NB;
    for (int b = tid; b < NB; b += 256) out[b] = h[b];
}

// ---------------- phase 1b: cross-block scan per bucket --------------------
// Block b scans hist[0..nblk)[b] -> baseT[blk][b] (exclusive) + bucketCnt[b].
__global__ __launch_bounds__(256) void blk_scan(const int* __restrict__ hist, int nblk, int NB,
                                                int* __restrict__ baseT,
                                                int* __restrict__ bucketCnt) {
    __shared__ int sd[256];
    __shared__ int carryS;
    int b = blockIdx.x, tid = threadIdx.x;
    if (tid == 0) carryS = 0;
    __syncthreads();
    for (int c0 = 0; c0 < nblk; c0 += 256) {
        int i = c0 + tid;
        int v = (i < nblk) ? hist[(size_t)i * NB + b] : 0;
        sd[tid] = v;
        __syncthreads();
        for (int off = 1; off < 256; off <<= 1) {
            int x = sd[tid];
            int y = (tid >= off) ? sd[tid - off] : 0;
            __syncthreads();
            sd[tid] = x + y;
            __syncthreads();
        }
        int carry = carryS;
        if (i < nblk) baseT[(size_t)i * NB + b] = carry + sd[tid] - v;
        __syncthreads();
        if (tid == 255) carryS = carry + sd[255];
        __syncthreads();
    }
    if (tid == 0) bucketCnt[b] = carryS;
}

// In-block exclusive scan of bucketCnt[0..NB) -> bOffs (2 buckets/thread).
__device__ __forceinline__ void scan_buckets(const int* __restrict__ bucketCnt, int NB,
                                             int* bOffs, int* sc) {
    int tid = threadIdx.x;
    int b0 = 2 * tid, b1 = 2 * tid + 1;
    int c0 = (b0 < NB) ? bucketCnt[b0] : 0;
    int c1 = (b1 < NB) ? bucketCnt[b1] : 0;
    int ts = c0 + c1;
    sc[tid] = ts;
    __syncthreads();
    for (int off = 1; off < 256; off <<= 1) {
        int x = sc[tid];
        int y = (tid >= off) ? sc[tid - off] : 0;
        __syncthreads();
        sc[tid] = x + y;
        __syncthreads();
    }
    int excl = sc[tid] - ts;
    bOffs[b0] = excl;
    bOffs[b1] = excl + c0;
    __syncthreads();
}

// ---------------- phase 1c: partition edges + (tail blocks) weight prep ----
__global__ __launch_bounds__(256) void partition_wprep(
    const int* __restrict__ src, const int* __restrict__ dst, int E, int NB, int partBlocks,
    const int* __restrict__ bucketCnt, const int* __restrict__ baseT,
    unsigned int* __restrict__ bucketBuf,
    const float* __restrict__ Wn1, const float* __restrict__ Ws1,
    const float* __restrict__ bn1, const float* __restrict__ bs1,
    const float* __restrict__ Wn2, const float* __restrict__ Ws2,
    const float* __restrict__ bn2, const float* __restrict__ bs2,
    unsigned short* __restrict__ Bpre, float* __restrict__ biasPre) {
    int tid = threadIdx.x;
    if ((int)blockIdx.x >= partBlocks) {
        // ---- weight prep: f32 W -> bf16 pre-swizzled fragments ----
        int wb = blockIdx.x - partBlocks;  // [0,32)
        int l = wb >> 4;
        const float* Wn = l ? Wn2 : Wn1;
        const float* Ws = l ? Ws2 : Ws1;
        int fi = (wb & 15) * 256 + tid;
        int kt = fi >> 9;
        int nt = (fi >> 6) & 7;
        int lane = fi & 63;
        int o = nt * 16 + (lane & 15);
        int k = kt * 32 + (lane >> 4) * 8;
        const float* srcp = (k < 128) ? (Wn + o * 128 + k) : (Ws + o * 128 + (k - 128));
        short8 v;
#pragma unroll
        for (int j = 0; j < 8; j++) v[j] = (short)f2bf(srcp[j]);
        ((short8*)(Bpre + (size_t)l * 32768))[fi] = v;
        if ((wb & 15) == 0 && tid < 128) {
            const float* bn = l ? bn2 : bn1;
            const float* bs = l ? bs2 : bs1;
            biasPre[l * 128 + tid] = bn[tid] + bs[tid];
        }
        return;
    }
    __shared__ int cnt[NBMAX];
    __shared__ int bOffs[NBMAX];
    __shared__ int gb[NBMAX];
    __shared__ int sc[256];
    scan_buckets(bucketCnt, NB, bOffs, sc);
    for (int b = tid; b < NB; b += 256) {
        cnt[b] = 0;
        gb[b] = bOffs[b] + baseT[(size_t)blockIdx.x * NB + b];
    }
    __syncthreads();
    int eb = blockIdx.x * 4096;
    unsigned int pk[16];
    int bk[16], rk[16];
    for (int i = 0; i < 16; i++) {
        int e = eb + i * 256 + tid;
        if (e < E) {
            int d = dst[e];
            bk[i] = d >> 8;
            pk[i] = (unsigned)src[e] | ((unsigned)(d & 255) << 24);
            rk[i] = atomicAdd(&cnt[bk[i]], 1);
        } else {
            bk[i] = -1;
        }
    }
    __syncthreads();
    for (int i = 0; i < 16; i++)
        if (bk[i] >= 0) bucketBuf[gb[bk[i]] + rk[i]] = pk[i];
}

// ---------------- phase 2: per-bucket CSR build + (tail blocks) x->bf16 ----
__global__ __launch_bounds__(256) void csrbuild_cvt(
    const unsigned int* __restrict__ bucketBuf, const int* __restrict__ bucketCnt,
    int N, int NB, int* __restrict__ deg, int* __restrict__ offs, int* __restrict__ sortedSrc,
    const float* __restrict__ xin, unsigned int* __restrict__ xb, int n2) {
    int tid = threadIdx.x;
    if ((int)blockIdx.x >= NB) {
        // ---- cvt: f32 [N,128] -> packed bf16 u32 [N,64], 8 u32/thread ----
        int cb = blockIdx.x - NB;
        int base = cb * 2048 + tid;
        if (xb) {
#pragma unroll
            for (int i = 0; i < 8; i++) {
                int t = base + i * 256;
                if (t < n2) {
                    float2 v = ((const float2*)xin)[t];
                    xb[t] = (unsigned)f2bf(v.x) | ((unsigned)f2bf(v.y) << 16);
                }
            }
        }
        return;
    }
    __shared__ int bOffs[NBMAX];
    __shared__ int h[256];
    __shared__ int sc[256];
    __shared__ int cur[256];
    scan_buckets(bucketCnt, NB, bOffs, sc);
    int b = blockIdx.x;
    int n0 = b << 8;
    int bo = bOffs[b];
    int cnt = bucketCnt[b];
    h[tid] = 0;
    __syncthreads();
    for (int i = tid; i < cnt; i += 256) atomicAdd(&h[bucketBuf[bo + i] >> 24], 1);
    __syncthreads();
    int v = h[tid];
    sc[tid] = v;
    __syncthreads();
    for (int off = 1; off < 256; off <<= 1) {
        int x = sc[tid];
        int y = (tid >= off) ? sc[tid - off] : 0;
        __syncthreads();
        sc[tid] = x + y;
        __syncthreads();
    }
    int excl = sc[tid] - v;
    cur[tid] = bo + excl;
    int n = n0 + tid;
    if (n < N) {
        deg[n] = v;
        offs[n] = bo + excl;
    }
    __syncthreads();
    for (int i = tid; i < cnt; i += 256) {
        unsigned int pv = bucketBuf[bo + i];
        int pos = atomicAdd(&cur[pv >> 24], 1);
        sortedSrc[pos] = (int)(pv & 0xFFFFFFu);
    }
}

// ---------------- mean agg, bf16 source (wave/node, 16-deep, SGPR bases) ----
__global__ __launch_bounds__(256) void agg_bf16_kernel(
    const unsigned int* __restrict__ srcFeats,
    const int* __restrict__ deg, const int* __restrict__ offs,
    const int* __restrict__ sortedSrc,
    unsigned int* __restrict__ dst, int Nn) {
    int wave = threadIdx.x >> 6, lane = threadIdx.x & 63;
    int n = blockIdx.x * 4 + wave;
    if (n >= Nn) return;
    int d = deg[n], st = offs[n];
    float a0 = 0.f, a1 = 0.f;
    int j = 0;
    for (; j + 16 <= d; j += 16) {
        unsigned int uu[16];
#pragma unroll
        for (int u = 0; u < 16; u++) {
            int s = __builtin_amdgcn_readfirstlane(sortedSrc[st + j + u]);
            uu[u] = (srcFeats + (size_t)s * 64)[lane];
        }
#pragma unroll
        for (int u = 0; u < 16; u++) {
            a0 += __uint_as_float(uu[u] << 16);
            a1 += __uint_as_float(uu[u] & 0xFFFF0000u);
        }
    }
    for (; j + 8 <= d; j += 8) {
        unsigned int uu[8];
#pragma unroll
        for (int u = 0; u < 8; u++) {
            int s = __builtin_amdgcn_readfirstlane(sortedSrc[st + j + u]);
            uu[u] = (srcFeats + (size_t)s * 64)[lane];
        }
#pragma unroll
        for (int u = 0; u < 8; u++) {
            a0 += __uint_as_float(uu[u] << 16);
            a1 += __uint_as_float(uu[u] & 0xFFFF0000u);
        }
    }
    for (; j < d; j++) {
        int s = __builtin_amdgcn_readfirstlane(sortedSrc[st + j]);
        unsigned int u = (srcFeats + (size_t)s * 64)[lane];
        a0 += __uint_as_float(u << 16);
        a1 += __uint_as_float(u & 0xFFFF0000u);
    }
    float inv = 1.0f / (float)max(d, 1);
    dst[(size_t)n * 64 + lane] = (unsigned)f2bf(a0 * inv) | ((unsigned)f2bf(a1 * inv) << 16);
}

// ---------------- mean agg, f32 source (fallback layout B) ------------------
__global__ __launch_bounds__(256) void agg_f32_kernel(
    const float* __restrict__ srcFeats,
    const int* __restrict__ deg, const int* __restrict__ offs,
    const int* __restrict__ sortedSrc,
    unsigned int* __restrict__ dst, int Nn) {
    int wave = threadIdx.x >> 6, lane = threadIdx.x & 63;
    int n = blockIdx.x * 4 + wave;
    if (n >= Nn) return;
    int d = deg[n], st = offs[n];
    float a0 = 0.f, a1 = 0.f;
    int j = 0;
    for (; j + 8 <= d; j += 8) {
        float2 v[8];
#pragma unroll
        for (int u = 0; u < 8; u++) {
            int s = __builtin_amdgcn_readfirstlane(sortedSrc[st + j + u]);
            v[u] = ((const float2*)(srcFeats + (size_t)s * 128))[lane];
        }
#pragma unroll
        for (int u = 0; u < 8; u++) {
            a0 += v[u].x;
            a1 += v[u].y;
        }
    }
    for (; j < d; j++) {
        int s = __builtin_amdgcn_readfirstlane(sortedSrc[st + j]);
        float2 v = ((const float2*)(srcFeats + (size_t)s * 128))[lane];
        a0 += v.x;
        a1 += v.y;
    }
    float inv = 1.0f / (float)max(d, 1);
    dst[(size_t)n * 64 + lane] = (unsigned)f2bf(a0 * inv) | ((unsigned)f2bf(a1 * inv) << 16);
}

// ---------------- fused GEMM: out = act([Aagg|Aself] @ B^T + bias) ---------
// R15: ALL 16 A fragments (2 mt x 8 kt) prefetched into registers with
// static indices BEFORE the MFMA loop -> single vmcnt wait instead of 8
// serialized load-stalls per tile. Row indices don't depend on kt.
// Out may alias Aself (fallback layer 2): each wave reads all its A rows
// before writing them -> safe. (No __restrict__ on Aself/Out.)
__global__ __launch_bounds__(256) void gemm_kernel(
    const unsigned short* __restrict__ Aagg, const void* Aself,
    const unsigned short* __restrict__ Bpre, const float* __restrict__ biasPre,
    void* Out, int relu, int selfF32, int outBf16, int Nrows) {
    __shared__ unsigned short ldsB[8 * 8 * 64 * 8];  // 64 KB
    __shared__ float biasS[128];
    int tid = threadIdx.x;

    // Pure coalesced copy: Bpre is already bf16 in fragment order.
#pragma unroll
    for (int i = 0; i < 16; i++) {
        int fi = tid + 256 * i;
        ((short8*)ldsB)[fi] = ((const short8*)Bpre)[fi];
    }
    if (tid < 128) biasS[tid] = biasPre[tid];
    __syncthreads();

    int wave = tid >> 6, lane = tid & 63;
    int quad = lane >> 4, mr = lane & 15;
    int rowBase = blockIdx.x * 128 + wave * 32;

    // ---- prefetch all A fragments (static unroll -> registers) ----
    short8 af[2][8];
#pragma unroll
    for (int mt = 0; mt < 2; mt++) {
        int row = rowBase + mt * 16 + mr;
        if (row >= Nrows) row = Nrows - 1;  // in-bounds; result discarded
        const unsigned short* pa = Aagg + (size_t)row * 128 + quad * 8;
#pragma unroll
        for (int kt = 0; kt < 4; kt++) af[mt][kt] = *(const short8*)(pa + kt * 32);
        if (selfF32) {
            const float* ps = (const float*)Aself + (size_t)row * 128 + quad * 8;
#pragma unroll
            for (int kt = 0; kt < 4; kt++) {
                float4_ f0 = *(const float4_*)(ps + kt * 32);
                float4_ f1 = *(const float4_*)(ps + kt * 32 + 4);
                short8 t;
#pragma unroll
                for (int j = 0; j < 4; j++) {
                    t[j] = (short)f2bf(f0[j]);
                    t[4 + j] = (short)f2bf(f1[j]);
                }
                af[mt][4 + kt] = t;
            }
        } else {
            const unsigned short* ps = (const unsigned short*)Aself + (size_t)row * 128 + quad * 8;
#pragma unroll
            for (int kt = 0; kt < 4; kt++) af[mt][4 + kt] = *(const short8*)(ps + kt * 32);
        }
    }

    float4_ acc[2][8];
    float4_ z = {0.f, 0.f, 0.f, 0.f};
#pragma unroll
    for (int mt = 0; mt < 2; mt++)
#pragma unroll
        for (int nt = 0; nt < 8; nt++) acc[mt][nt] = z;

#pragma unroll
    for (int kt = 0; kt < 8; kt++) {
#pragma unroll
        for (int nt = 0; nt < 8; nt++) {
            short8 b = *(const short8*)(ldsB + ((size_t)(kt * 8 + nt) * 64 + lane) * 8);
            acc[0][nt] = __builtin_amdgcn_mfma_f32_16x16x32_bf16(af[0][kt], b, acc[0][nt], 0, 0, 0);
            acc[1][nt] = __builtin_amdgcn_mfma_f32_16x16x32_bf16(af[1][kt], b, acc[1][nt], 0, 0, 0);
        }
    }

    // C/D layout: col = lane&15, row = (lane>>4)*4 + reg
    for (int mt = 0; mt < 2; mt++) {
        for (int nt = 0; nt < 8; nt++) {
            int col = nt * 16 + mr;
            float bv = biasS[col];
            for (int r = 0; r < 4; r++) {
                int row = rowBase + mt * 16 + quad * 4 + r;
                if (row < Nrows) {
                    float v = acc[mt][nt][r] + bv;
                    if (relu) v = fmaxf(v, 0.f);
                    if (outBf16)
                        ((unsigned short*)Out)[(size_t)row * 128 + col] = f2bf(v);
                    else
                        ((float*)Out)[(size_t)row * 128 + col] = v;
                }
            }
        }
    }
}

extern "C" void kernel_launch(void* const* d_in, const int* in_sizes, int n_in,
                              void* d_out, int out_size, void* d_ws, size_t ws_size,
                              hipStream_t stream) {
    const float* x = (const float*)d_in[0];
    const int* ei = (const int*)d_in[1];
    const float* Wn1 = (const float*)d_in[2];
    const float* bn1 = (const float*)d_in[3];
    const float* Ws1 = (const float*)d_in[4];
    const float* bs1 = (const float*)d_in[5];
    const float* Wn2 = (const float*)d_in[6];
    const float* bn2 = (const float*)d_in[7];
    const float* Ws2 = (const float*)d_in[8];
    const float* bs2 = (const float*)d_in[9];

    const int N = in_sizes[0] / 128;
    const int E = in_sizes[1] / 2;
    const int* srcI = ei;
    const int* dstI = ei + E;
    const int NB = (N + 255) >> 8;      // <= NBMAX for N <= 131072
    const int ebBlocks = (E + 4095) / 4096;

    char* ws = (char*)d_ws;
    size_t off = 0;
    auto alloc = [&](size_t bytes) -> void* {
        void* p = ws + off;
        off += (bytes + 255) & ~(size_t)255;
        return p;
    };
    int* deg = (int*)alloc((size_t)N * 4);
    int* offs = (int*)alloc((size_t)N * 4);
    int* bucketCnt = (int*)alloc((NBMAX + 1) * 4);
    int* hist = (int*)alloc((size_t)ebBlocks * NB * 4);
    int* baseT = (int*)alloc((size_t)ebBlocks * NB * 4);
    unsigned short* Bpre = (unsigned short*)alloc(2 * 32768 * 2);
    float* biasPre = (float*)alloc(2 * 128 * 4);
    int* sortedSrc = (int*)alloc((size_t)E * 4);
    unsigned short* Aagg = (unsigned short*)alloc((size_t)N * 128 * 2);
    size_t baseNeed = off;
    size_t bf16Buf = ((size_t)N * 128 * 2 + 255) & ~(size_t)255;
    bool bigWs = (ws_size >= baseNeed + 2 * bf16Buf);
    unsigned int* xb = nullptr;
    unsigned short* h1b = nullptr;
    if (bigWs) {
        xb = (unsigned int*)alloc((size_t)N * 128 * 2);
        h1b = (unsigned short*)alloc((size_t)N * 128 * 2);
    }
    // bucketBuf (E u32, 6.4 MB) aliases Aagg (dead until agg1)
    unsigned int* bucketBuf = (unsigned int*)Aagg;

    // ---- CSR build (atomic-free bucketing, self-scanned offsets) ----
    int n2 = N * 64;
    int cvtBlocks = bigWs ? (n2 + 2047) / 2048 : 0;
    bucket_count<<<ebBlocks, 256, 0, stream>>>(dstI, E, NB, hist);
    blk_scan<<<NB, 256, 0, stream>>>(hist, ebBlocks, NB, baseT, bucketCnt);
    partition_wprep<<<ebBlocks + 32, 256, 0, stream>>>(
        srcI, dstI, E, NB, ebBlocks, bucketCnt, baseT, bucketBuf,
        Wn1, Ws1, bn1, bs1, Wn2, Ws2, bn2, bs2, Bpre, biasPre);
    csrbuild_cvt<<<NB + cvtBlocks, 256, 0, stream>>>(bucketBuf, bucketCnt, N, NB, deg, offs,
                                                     sortedSrc, x, xb, n2);

    int aggBlocks = (N + 3) / 4;
    int gemmBlocks = (N + 127) / 128;

    if (bigWs) {
        // Layout A: all gathers bf16 (256 B/row)
        agg_bf16_kernel<<<aggBlocks, 256, 0, stream>>>(xb, deg, offs, sortedSrc,
                                                       (unsigned int*)Aagg, N);
        gemm_kernel<<<gemmBlocks, 256, 0, stream>>>(Aagg, xb, Bpre, biasPre, h1b, 1, 0, 1, N);
        agg_bf16_kernel<<<aggBlocks, 256, 0, stream>>>((const unsigned int*)h1b, deg, offs,
                                                       sortedSrc, (unsigned int*)Aagg, N);
        gemm_kernel<<<gemmBlocks, 256, 0, stream>>>(Aagg, h1b, Bpre + 32768, biasPre + 128,
                                                    d_out, 0, 0, 0, N);
    } else {
        // Layout B: f32 gathers, h1 f32 staged in d_out
        float* h1 = (float*)d_out;
        agg_f32_kernel<<<aggBlocks, 256, 0, stream>>>(x, deg, offs, sortedSrc,
                                                      (unsigned int*)Aagg, N);
        gemm_kernel<<<gemmBlocks, 256, 0, stream>>>(Aagg, x, Bpre, biasPre, h1, 1, 1, 0, N);
        agg_f32_kernel<<<aggBlocks, 256, 0, stream>>>(h1, deg, offs, sortedSrc,
                                                      (unsigned int*)Aagg, N);
        gemm_kernel<<<gemmBlocks, 256, 0, stream>>>(Aagg, h1, Bpre + 32768, biasPre + 128,
                                                    d_out, 0, 1, 0, N);
    }
}